// Round 12
// baseline (565.240 us; speedup 1.0000x reference)
//
#include <hip/hip_runtime.h>
#include <math.h>

#define NROWS 8192
#define DIMS 64
#define NUM_BW 10

#define BM 128
#define BN 128
#define TM 8
#define TN 8
#define LDK 36   // 32 floats per K-half + 4 pad

#define TAB_SEGS 512      // g(d) table: [0,512), h=1, cubic Hermite per segment
#define TAB_MAXI 511.0f

// One wave per row: log_softmax + row squared-norm (fp64 reduce for the norm).
__global__ __launch_bounds__(256) void lsm_norm_kernel(
    const float* __restrict__ in, float* __restrict__ out, float* __restrict__ norms)
{
    int wave = threadIdx.x >> 6;
    int lane = threadIdx.x & 63;
    int row = blockIdx.x * 4 + wave;
    float v = in[row * DIMS + lane];
    float m = v;
#pragma unroll
    for (int off = 32; off >= 1; off >>= 1)
        m = fmaxf(m, __shfl_xor(m, off));
    float e = expf(v - m);
    float s = e;
#pragma unroll
    for (int off = 32; off >= 1; off >>= 1)
        s += __shfl_xor(s, off);
    float lse = m + logf(s);
    float o = v - lse;
    out[row * DIMS + lane] = o;
    double q = (double)o * (double)o;
#pragma unroll
    for (int off = 32; off >= 1; off >>= 1)
        q += __shfl_xor(q, off);
    if (lane == 0) norms[row] = (float)q;
}

// Build per-segment cubic Hermite coeffs for g(d) = sum_k exp(-c_k d), fp64.
__global__ void build_table_kernel(float4* __restrict__ tab)
{
    int i = blockIdx.x * 256 + threadIdx.x;
    if (i >= TAB_SEGS) return;
    double x0 = (double)i, x1 = x0 + 1.0;
    double g0 = 0, g1 = 0, p0 = 0, p1 = 0;
    for (int k = 0; k < NUM_BW; ++k) {
        double bw = pow(128.0, (double)k / 9.0);
        double c = 0.5 / (bw * bw);
        double e0 = exp(-c * x0), e1 = exp(-c * x1);
        g0 += e0; g1 += e1;
        p0 -= c * e0; p1 -= c * e1;
    }
    // cubic in t on [0,1): a0 + t(a1 + t(a2 + t a3)); exact values+derivs at ends
    float4 cf;
    cf.x = (float)g0;
    cf.y = (float)p0;
    cf.z = (float)(3.0 * (g1 - g0) - 2.0 * p0 - p1);
    cf.w = (float)(2.0 * (g0 - g1) + p0 + p1);
    tab[i] = cf;
}

// z=0: XX (upper triangle), z=1: YY, z=2: XY (w=-2, full).
__global__ __launch_bounds__(256, 3) void pair_kernel(
    const float* __restrict__ X, const float* __restrict__ Y,
    const float* __restrict__ AA, const float* __restrict__ BB,
    const float4* __restrict__ gtab, double* __restrict__ acc_out)
{
    const int z = blockIdx.z;
    const int bi = blockIdx.x, bj = blockIdx.y;
    double w;
    const float *A, *B, *aa, *bb;
    if (z == 0)      { A = X; B = X; aa = AA; bb = AA; }
    else if (z == 1) { A = Y; B = Y; aa = BB; bb = BB; }
    else             { A = X; B = Y; aa = AA; bb = BB; }
    if (z < 2) {
        if (bj < bi) return;               // symmetric: skip lower triangle
        w = (bj == bi) ? 1.0 : 2.0;
    } else {
        w = -2.0;
    }

    __shared__ float As[BM][LDK];
    __shared__ float Bs[BN][LDK];
    __shared__ float4 tabs[TAB_SEGS];      // 8 KB
    __shared__ double wsum[4];

    const int tid = threadIdx.x;
    const int tr = tid >> 4;
    const int tc = tid & 15;
    const int i0 = bi * BM, j0 = bj * BN;

    for (int i = tid; i < TAB_SEGS; i += 256) tabs[i] = gtab[i];

    float accv[TM][TN];
#pragma unroll
    for (int a = 0; a < TM; ++a)
#pragma unroll
        for (int b = 0; b < TN; ++b) accv[a][b] = 0.f;

    for (int kh = 0; kh < DIMS; kh += 32) {
        __syncthreads();
#pragma unroll
        for (int p = 0; p < 4; ++p) {
            int idx = tid + p * 256;
            int row = idx >> 3;
            int kc  = (idx & 7) << 2;
            *reinterpret_cast<float4*>(&As[row][kc]) =
                *reinterpret_cast<const float4*>(&A[(size_t)(i0 + row) * DIMS + kh + kc]);
            *reinterpret_cast<float4*>(&Bs[row][kc]) =
                *reinterpret_cast<const float4*>(&B[(size_t)(j0 + row) * DIMS + kh + kc]);
        }
        __syncthreads();
#pragma unroll
        for (int kg = 0; kg < 32; kg += 4) {
            float4 a4[TM], b4[TN];
#pragma unroll
            for (int mi = 0; mi < TM; ++mi)
                a4[mi] = *reinterpret_cast<const float4*>(&As[mi * 16 + tr][kg]);
#pragma unroll
            for (int mj = 0; mj < TN; ++mj)
                b4[mj] = *reinterpret_cast<const float4*>(&Bs[mj * 16 + tc][kg]);
#pragma unroll
            for (int mi = 0; mi < TM; ++mi)
#pragma unroll
                for (int mj = 0; mj < TN; ++mj) {
                    float t = accv[mi][mj];
                    t = fmaf(a4[mi].x, b4[mj].x, t);
                    t = fmaf(a4[mi].y, b4[mj].y, t);
                    t = fmaf(a4[mi].z, b4[mj].z, t);
                    t = fmaf(a4[mi].w, b4[mj].w, t);
                    accv[mi][mj] = t;
                }
        }
    }

    float av[TM], bv[TN];
#pragma unroll
    for (int mi = 0; mi < TM; ++mi) av[mi] = aa[i0 + mi * 16 + tr];
#pragma unroll
    for (int mj = 0; mj < TN; ++mj) bv[mj] = bb[j0 + mj * 16 + tc];

    double th = 0.0;
#pragma unroll
    for (int mi = 0; mi < TM; ++mi) {
        float rs = 0.f;
        float avmi = av[mi];
#pragma unroll
        for (int mj = 0; mj < TN; ++mj) {
            float d = fmaf(-2.0f, accv[mi][mj], avmi + bv[mj]);
            d = fmaxf(d, 0.0f);
            float fi = truncf(d);
            fi = fminf(fi, TAB_MAXI);
            float t = d - fi;
            t = fminf(t, 1.0f);            // safety if d beyond table range
            float4 cf = tabs[(int)fi];
            rs += fmaf(fmaf(fmaf(cf.w, t, cf.z), t, cf.y), t, cf.x);
        }
        th += (double)rs;
    }

#pragma unroll
    for (int off = 32; off >= 1; off >>= 1)
        th += __shfl_xor(th, off);
    if ((tid & 63) == 0) wsum[tid >> 6] = th;
    __syncthreads();
    if (tid == 0) {
        double t = (wsum[0] + wsum[1]) + (wsum[2] + wsum[3]);
        atomicAdd(acc_out, w * t);
    }
}

__global__ void finalize_kernel(const double* __restrict__ acc, float* __restrict__ out)
{
    out[0] = (float)(acc[0] / ((double)NROWS * (double)NROWS * (double)NUM_BW));
}

extern "C" void kernel_launch(void* const* d_in, const int* in_sizes, int n_in,
                              void* d_out, int out_size, void* d_ws, size_t ws_size,
                              hipStream_t stream)
{
    const float* src = (const float*)d_in[0];
    const float* tgt = (const float*)d_in[1];
    float* out = (float*)d_out;

    char* ws = (char*)d_ws;
    float* x_ls = (float*)ws;                       // 2 MB
    float* y_ls = x_ls + (size_t)NROWS * DIMS;      // 2 MB
    float* aa   = y_ls + (size_t)NROWS * DIMS;      // 32 KB
    float* bb   = aa + NROWS;                       // 32 KB
    float4* tab = (float4*)(bb + NROWS);            // 8 KB, 16B-aligned
    double* acc = (double*)(tab + TAB_SEGS);        // 8 B

    hipMemsetAsync(acc, 0, sizeof(double), stream);

    lsm_norm_kernel<<<NROWS / 4, 256, 0, stream>>>(src, x_ls, aa);
    lsm_norm_kernel<<<NROWS / 4, 256, 0, stream>>>(tgt, y_ls, bb);
    build_table_kernel<<<2, 256, 0, stream>>>(tab);

    dim3 grid(NROWS / BM, NROWS / BN, 3);
    pair_kernel<<<grid, 256, 0, stream>>>(x_ls, y_ls, aa, bb, tab, acc);
    finalize_kernel<<<1, 1, 0, stream>>>(acc, out);
}

// Round 13
// 379.680 us; speedup vs baseline: 1.4887x; 1.4887x over previous
//
#include <hip/hip_runtime.h>
#include <math.h>

#define NROWS 8192
#define DIMS 64
#define NUM_BW 10

#define BM 128
#define BN 128
#define TM 8
#define TN 8
#define LDK 36   // 32 floats per K-half + 4 pad

#define TAB_SEGS 512      // g(d) table: [0,512), h=1, cubic Hermite per segment
#define TAB_MAXI 511.0f

// One wave per row: log_softmax + row squared-norm (fp64 reduce for the norm).
__global__ __launch_bounds__(256) void lsm_norm_kernel(
    const float* __restrict__ in, float* __restrict__ out, float* __restrict__ norms)
{
    int wave = threadIdx.x >> 6;
    int lane = threadIdx.x & 63;
    int row = blockIdx.x * 4 + wave;
    float v = in[row * DIMS + lane];
    float m = v;
#pragma unroll
    for (int off = 32; off >= 1; off >>= 1)
        m = fmaxf(m, __shfl_xor(m, off));
    float e = expf(v - m);
    float s = e;
#pragma unroll
    for (int off = 32; off >= 1; off >>= 1)
        s += __shfl_xor(s, off);
    float lse = m + logf(s);
    float o = v - lse;
    out[row * DIMS + lane] = o;
    double q = (double)o * (double)o;
#pragma unroll
    for (int off = 32; off >= 1; off >>= 1)
        q += __shfl_xor(q, off);
    if (lane == 0) norms[row] = (float)q;
}

// Build per-segment cubic Hermite coeffs for g(d) = sum_k exp(-c_k d), fp64.
__global__ void build_table_kernel(float4* __restrict__ tab)
{
    int i = blockIdx.x * 256 + threadIdx.x;
    if (i >= TAB_SEGS) return;
    double x0 = (double)i, x1 = x0 + 1.0;
    double g0 = 0, g1 = 0, p0 = 0, p1 = 0;
    for (int k = 0; k < NUM_BW; ++k) {
        double bw = pow(128.0, (double)k / 9.0);
        double c = 0.5 / (bw * bw);
        double e0 = exp(-c * x0), e1 = exp(-c * x1);
        g0 += e0; g1 += e1;
        p0 -= c * e0; p1 -= c * e1;
    }
    // cubic in t on [0,1): a0 + t(a1 + t(a2 + t a3)); exact values+derivs at ends
    float4 cf;
    cf.x = (float)g0;
    cf.y = (float)p0;
    cf.z = (float)(3.0 * (g1 - g0) - 2.0 * p0 - p1);
    cf.w = (float)(2.0 * (g0 - g1) + p0 + p1);
    tab[i] = cf;
}

// z=0: XX (upper triangle), z=1: YY, z=2: XY (w=-2, full).
// NOTE: launch_bounds (256,2) — the (256,3) occupancy hint capped VGPR at 84
// and spilled the 8x8 accumulator tile to scratch (847 MB HBM writes, r12).
__global__ __launch_bounds__(256, 2) void pair_kernel(
    const float* __restrict__ X, const float* __restrict__ Y,
    const float* __restrict__ AA, const float* __restrict__ BB,
    const float4* __restrict__ gtab, double* __restrict__ acc_out)
{
    const int z = blockIdx.z;
    const int bi = blockIdx.x, bj = blockIdx.y;
    double w;
    const float *A, *B, *aa, *bb;
    if (z == 0)      { A = X; B = X; aa = AA; bb = AA; }
    else if (z == 1) { A = Y; B = Y; aa = BB; bb = BB; }
    else             { A = X; B = Y; aa = AA; bb = BB; }
    if (z < 2) {
        if (bj < bi) return;               // symmetric: skip lower triangle
        w = (bj == bi) ? 1.0 : 2.0;
    } else {
        w = -2.0;
    }

    __shared__ float As[BM][LDK];
    __shared__ float Bs[BN][LDK];
    __shared__ float4 tabs[TAB_SEGS];      // 8 KB
    __shared__ double wsum[4];

    const int tid = threadIdx.x;
    const int tr = tid >> 4;
    const int tc = tid & 15;
    const int i0 = bi * BM, j0 = bj * BN;

    for (int i = tid; i < TAB_SEGS; i += 256) tabs[i] = gtab[i];

    float accv[TM][TN];
#pragma unroll
    for (int a = 0; a < TM; ++a)
#pragma unroll
        for (int b = 0; b < TN; ++b) accv[a][b] = 0.f;

    for (int kh = 0; kh < DIMS; kh += 32) {
        __syncthreads();
#pragma unroll
        for (int p = 0; p < 4; ++p) {
            int idx = tid + p * 256;
            int row = idx >> 3;
            int kc  = (idx & 7) << 2;
            *reinterpret_cast<float4*>(&As[row][kc]) =
                *reinterpret_cast<const float4*>(&A[(size_t)(i0 + row) * DIMS + kh + kc]);
            *reinterpret_cast<float4*>(&Bs[row][kc]) =
                *reinterpret_cast<const float4*>(&B[(size_t)(j0 + row) * DIMS + kh + kc]);
        }
        __syncthreads();
#pragma unroll
        for (int kg = 0; kg < 32; kg += 4) {
            float4 a4[TM], b4[TN];
#pragma unroll
            for (int mi = 0; mi < TM; ++mi)
                a4[mi] = *reinterpret_cast<const float4*>(&As[mi * 16 + tr][kg]);
#pragma unroll
            for (int mj = 0; mj < TN; ++mj)
                b4[mj] = *reinterpret_cast<const float4*>(&Bs[mj * 16 + tc][kg]);
#pragma unroll
            for (int mi = 0; mi < TM; ++mi)
#pragma unroll
                for (int mj = 0; mj < TN; ++mj) {
                    float t = accv[mi][mj];
                    t = fmaf(a4[mi].x, b4[mj].x, t);
                    t = fmaf(a4[mi].y, b4[mj].y, t);
                    t = fmaf(a4[mi].z, b4[mj].z, t);
                    t = fmaf(a4[mi].w, b4[mj].w, t);
                    accv[mi][mj] = t;
                }
        }
    }

    float av[TM], bv[TN];
#pragma unroll
    for (int mi = 0; mi < TM; ++mi) av[mi] = aa[i0 + mi * 16 + tr];
#pragma unroll
    for (int mj = 0; mj < TN; ++mj) bv[mj] = bb[j0 + mj * 16 + tc];

    double th = 0.0;
#pragma unroll
    for (int mi = 0; mi < TM; ++mi) {
        float rs = 0.f;
        float avmi = av[mi];
#pragma unroll
        for (int mj = 0; mj < TN; ++mj) {
            float d = fmaf(-2.0f, accv[mi][mj], avmi + bv[mj]);
            d = fmaxf(d, 0.0f);
            float fi = truncf(d);
            fi = fminf(fi, TAB_MAXI);
            float t = d - fi;
            t = fminf(t, 1.0f);            // safety if d beyond table range
            float4 cf = tabs[(int)fi];
            rs += fmaf(fmaf(fmaf(cf.w, t, cf.z), t, cf.y), t, cf.x);
        }
        th += (double)rs;
    }

#pragma unroll
    for (int off = 32; off >= 1; off >>= 1)
        th += __shfl_xor(th, off);
    if ((tid & 63) == 0) wsum[tid >> 6] = th;
    __syncthreads();
    if (tid == 0) {
        double t = (wsum[0] + wsum[1]) + (wsum[2] + wsum[3]);
        atomicAdd(acc_out, w * t);
    }
}

__global__ void finalize_kernel(const double* __restrict__ acc, float* __restrict__ out)
{
    out[0] = (float)(acc[0] / ((double)NROWS * (double)NROWS * (double)NUM_BW));
}

extern "C" void kernel_launch(void* const* d_in, const int* in_sizes, int n_in,
                              void* d_out, int out_size, void* d_ws, size_t ws_size,
                              hipStream_t stream)
{
    const float* src = (const float*)d_in[0];
    const float* tgt = (const float*)d_in[1];
    float* out = (float*)d_out;

    char* ws = (char*)d_ws;
    float* x_ls = (float*)ws;                       // 2 MB
    float* y_ls = x_ls + (size_t)NROWS * DIMS;      // 2 MB
    float* aa   = y_ls + (size_t)NROWS * DIMS;      // 32 KB
    float* bb   = aa + NROWS;                       // 32 KB
    float4* tab = (float4*)(bb + NROWS);            // 8 KB, 16B-aligned
    double* acc = (double*)(tab + TAB_SEGS);        // 8 B

    hipMemsetAsync(acc, 0, sizeof(double), stream);

    lsm_norm_kernel<<<NROWS / 4, 256, 0, stream>>>(src, x_ls, aa);
    lsm_norm_kernel<<<NROWS / 4, 256, 0, stream>>>(tgt, y_ls, bb);
    build_table_kernel<<<2, 256, 0, stream>>>(tab);

    dim3 grid(NROWS / BM, NROWS / BN, 3);
    pair_kernel<<<grid, 256, 0, stream>>>(x_ls, y_ls, aa, bb, tab, acc);
    finalize_kernel<<<1, 1, 0, stream>>>(acc, out);
}

// Round 14
// 202.368 us; speedup vs baseline: 2.7931x; 1.8762x over previous
//
#include <hip/hip_runtime.h>
#include <math.h>

#define NROWS 8192
#define DIMS 64
#define NUM_BW 10
#define BM 128

#define TAB_SEGS 512      // g(d) table: [0,512), h=1, cubic Hermite per segment
#define TAB_MAXI 511.0f

typedef short bf16x8 __attribute__((ext_vector_type(8)));   // 8 bf16 bit-patterns (guide-verified MFMA operand type)
typedef float f32x16 __attribute__((ext_vector_type(16)));

static __device__ __forceinline__ short f2bf_rne(float v) {
    unsigned u = __builtin_bit_cast(unsigned, v);
    unsigned r = (u + 0x7fffu + ((u >> 16) & 1u)) >> 16;
    return (short)r;
}
static __device__ __forceinline__ float bf2f(short h) {
    return __builtin_bit_cast(float, (unsigned)((unsigned short)h) << 16);
}

// One wave per row: log_softmax + row squared-norm (fp64 reduce for the norm).
__global__ __launch_bounds__(256) void lsm_norm_kernel(
    const float* __restrict__ in, float* __restrict__ out, float* __restrict__ norms)
{
    int wave = threadIdx.x >> 6;
    int lane = threadIdx.x & 63;
    int row = blockIdx.x * 4 + wave;
    float v = in[row * DIMS + lane];
    float m = v;
#pragma unroll
    for (int off = 32; off >= 1; off >>= 1)
        m = fmaxf(m, __shfl_xor(m, off));
    float e = expf(v - m);
    float s = e;
#pragma unroll
    for (int off = 32; off >= 1; off >>= 1)
        s += __shfl_xor(s, off);
    float lse = m + logf(s);
    float o = v - lse;
    out[row * DIMS + lane] = o;
    double q = (double)o * (double)o;
#pragma unroll
    for (int off = 32; off >= 1; off >>= 1)
        q += __shfl_xor(q, off);
    if (lane == 0) norms[row] = (float)q;
}

// Build per-segment cubic Hermite coeffs for g(d) = sum_k exp(-c_k d), fp64.
__global__ void build_table_kernel(float4* __restrict__ tab)
{
    int i = blockIdx.x * 256 + threadIdx.x;
    if (i >= TAB_SEGS) return;
    double x0 = (double)i, x1 = x0 + 1.0;
    double g0 = 0, g1 = 0, p0 = 0, p1 = 0;
    for (int k = 0; k < NUM_BW; ++k) {
        double bw = pow(128.0, (double)k / 9.0);
        double c = 0.5 / (bw * bw);
        double e0 = exp(-c * x0), e1 = exp(-c * x1);
        g0 += e0; g1 += e1;
        p0 -= c * e0; p1 -= c * e1;
    }
    float4 cf;
    cf.x = (float)g0;
    cf.y = (float)p0;
    cf.z = (float)(3.0 * (g1 - g0) - 2.0 * p0 - p1);
    cf.w = (float)(2.0 * (g0 - g1) + p0 + p1);
    tab[i] = cf;
}

// Repack f32 row-major [8192][64] into split-bf16 fragment-major planes:
// pack[plane][rowtile(256)][kstep(4)][lane(64)][8] where
// row = rowtile*32 + (lane&31), k = kstep*16 + (lane>>5)*8 + j.
// This makes pair_kernel's global_load_lds (linear dest) AND its per-lane
// ds_read_b128 frag reads both fully linear/conflict-free.
__global__ __launch_bounds__(256) void repack_kernel(
    const float* __restrict__ x_ls, const float* __restrict__ y_ls,
    short* __restrict__ xp, short* __restrict__ yp)
{
    int idx = blockIdx.x * 256 + threadIdx.x;   // 0 .. 262143
    int mat   = idx >> 17;
    int rem   = idx & 131071;
    int plane = rem >> 16;
    int c     = rem & 65535;
    int rt    = c >> 8;
    int ks    = (c >> 6) & 3;
    int lane  = c & 63;
    int r  = rt * 32 + (lane & 31);
    int kb = ks * 16 + (lane >> 5) * 8;
    const float* src = (mat ? y_ls : x_ls) + r * DIMS + kb;
    bf16x8 o;
#pragma unroll
    for (int j = 0; j < 8; ++j) {
        float v = src[j];
        short h = f2bf_rne(v);
        o[j] = plane ? f2bf_rne(v - bf2f(h)) : h;
    }
    short* dst = (mat ? yp : xp) + ((size_t)((plane * 256 + rt) * 4 + ks) << 9) + lane * 8;
    *reinterpret_cast<bf16x8*>(dst) = o;
}

// z=0: XX (upper triangle), z=1: YY, z=2: XY (w=-2, full).
// 4 waves (2x2), each owns a 64x64 output tile = 2x2 MFMA 32x32 tiles.
// Split-bf16: ab = hi*hi + hi*lo + lo*hi accumulated by 3 MFMA passes.
__global__ __launch_bounds__(256) void pair_kernel(
    const short* __restrict__ Xp, const short* __restrict__ Yp,
    const float* __restrict__ AA, const float* __restrict__ BB,
    const float4* __restrict__ gtab, double* __restrict__ acc_out)
{
    const int z = blockIdx.z;
    const int bi = blockIdx.x, bj = blockIdx.y;
    double w;
    const short *Ap, *Bp;
    const float *aa, *bb;
    if (z == 0)      { Ap = Xp; Bp = Xp; aa = AA; bb = AA; }
    else if (z == 1) { Ap = Yp; Bp = Yp; aa = BB; bb = BB; }
    else             { Ap = Xp; Bp = Yp; aa = AA; bb = BB; }
    if (z < 2) {
        if (bj < bi) return;               // symmetric: skip lower triangle
        w = (bj == bi) ? 1.0 : 2.0;
    } else {
        w = -2.0;
    }

    // LDS: double-buffered k-step tiles. Per buf: [side(2)][plane(2)][rt(4)][64 lanes][16B] = 16KB.
    __shared__ char ldsbuf[32768];
    __shared__ float4 tabs[TAB_SEGS];      // 8 KB
    __shared__ float aas[BM], bbs[BM];
    __shared__ double wsum[4];

    const int tid  = threadIdx.x;
    const int lane = tid & 63;
    const int wid  = tid >> 6;
    const int wh   = wid >> 1;             // wave row (0/1)
    const int ww   = wid & 1;              // wave col (0/1)

    for (int i = tid; i < TAB_SEGS; i += 256) tabs[i] = gtab[i];
    if (tid < 128) aas[tid] = aa[bi * BM + tid];
    else           bbs[tid - 128] = bb[bj * BM + (tid - 128)];

    // --- staging: 16 chunks of 1KB per k-step, 4 per wave, async into LDS ---
    auto STAGE = [&](int ks, int buf) {
#pragma unroll
        for (int i = 0; i < 4; ++i) {
            int idx   = wid * 4 + i;              // 0..15
            int side  = idx >> 3;                 // 0=A, 1=B
            int plane = (idx >> 2) & 1;           // 0=hi, 1=lo
            int rt    = idx & 3;
            const short* mp = side ? Bp : Ap;
            int rtg = (side ? bj : bi) * 4 + rt;
            const short* gsrc = mp + ((size_t)((plane * 256 + rtg) * 4 + ks) << 9) + lane * 8;
            char* lp = ldsbuf + buf * 16384 + ((side * 2 + plane) * 4 + rt) * 1024;
            __builtin_amdgcn_global_load_lds(
                (const __attribute__((address_space(1))) void*)gsrc,
                (__attribute__((address_space(3))) void*)lp, 16, 0, 0);
        }
    };

    f32x16 acc[2][2];
#pragma unroll
    for (int m = 0; m < 2; ++m)
#pragma unroll
        for (int n = 0; n < 2; ++n) acc[m][n] = (f32x16)0.0f;

    STAGE(0, 0);
#pragma unroll
    for (int ks = 0; ks < 4; ++ks) {
        __syncthreads();                   // drains vmcnt: buf[cur] ready
        int cur = ks & 1;
        if (ks < 3) STAGE(ks + 1, cur ^ 1);
        const char* base = ldsbuf + cur * 16384;
        bf16x8 af[2][2], bfr[2][2];        // [tile][plane]
#pragma unroll
        for (int m = 0; m < 2; ++m)
#pragma unroll
            for (int p = 0; p < 2; ++p) {
                af[m][p]  = *reinterpret_cast<const bf16x8*>(base + ((0 + p) * 4 + (wh * 2 + m)) * 1024 + lane * 16);
                bfr[m][p] = *reinterpret_cast<const bf16x8*>(base + ((2 + p) * 4 + (ww * 2 + m)) * 1024 + lane * 16);
            }
#pragma unroll
        for (int m = 0; m < 2; ++m)
#pragma unroll
            for (int n = 0; n < 2; ++n) {
                acc[m][n] = __builtin_amdgcn_mfma_f32_32x32x16_bf16(af[m][0], bfr[n][0], acc[m][n], 0, 0, 0);
                acc[m][n] = __builtin_amdgcn_mfma_f32_32x32x16_bf16(af[m][0], bfr[n][1], acc[m][n], 0, 0, 0);
                acc[m][n] = __builtin_amdgcn_mfma_f32_32x32x16_bf16(af[m][1], bfr[n][0], acc[m][n], 0, 0, 0);
            }
    }

    // --- epilogue: C layout (32x32): col=lane&31, row=(reg&3)+8*(reg>>2)+4*(lane>>5) ---
    const int colb = ww * 64 + (lane & 31);
    const int rowb = wh * 64 + 4 * (lane >> 5);
    double th = 0.0;
#pragma unroll
    for (int m = 0; m < 2; ++m)
#pragma unroll
        for (int n = 0; n < 2; ++n) {
            float bv = bbs[colb + n * 32];
            float rs = 0.f;
            f32x16 creg = acc[m][n];
#pragma unroll
            for (int reg = 0; reg < 16; ++reg) {
                int rl = (reg & 3) + 8 * (reg >> 2);
                float av = aas[rowb + m * 32 + rl];
                float d = fmaf(-2.0f, creg[reg], av + bv);
                d = fmaxf(d, 0.0f);
                float fi = truncf(d);
                fi = fminf(fi, TAB_MAXI);
                float t = d - fi;
                t = fminf(t, 1.0f);
                float4 cf = tabs[(int)fi];
                rs += fmaf(fmaf(fmaf(cf.w, t, cf.z), t, cf.y), t, cf.x);
            }
            th += (double)rs;
        }

#pragma unroll
    for (int off = 32; off >= 1; off >>= 1)
        th += __shfl_xor(th, off);
    if (lane == 0) wsum[wid] = th;
    __syncthreads();
    if (tid == 0) {
        double t = (wsum[0] + wsum[1]) + (wsum[2] + wsum[3]);
        atomicAdd(acc_out, w * t);
    }
}

__global__ void finalize_kernel(const double* __restrict__ acc, float* __restrict__ out)
{
    out[0] = (float)(acc[0] / ((double)NROWS * (double)NROWS * (double)NUM_BW));
}

extern "C" void kernel_launch(void* const* d_in, const int* in_sizes, int n_in,
                              void* d_out, int out_size, void* d_ws, size_t ws_size,
                              hipStream_t stream)
{
    const float* src = (const float*)d_in[0];
    const float* tgt = (const float*)d_in[1];
    float* out = (float*)d_out;

    char* ws = (char*)d_ws;
    float* x_ls = (float*)ws;                         // 2 MB
    float* y_ls = x_ls + (size_t)NROWS * DIMS;        // 2 MB
    short* xp   = (short*)(y_ls + (size_t)NROWS * DIMS);  // 2 MB (hi+lo planes)
    short* yp   = xp + (size_t)NROWS * DIMS * 2;      // 2 MB
    float* aan  = (float*)(yp + (size_t)NROWS * DIMS * 2);  // 32 KB
    float* bbn  = aan + NROWS;                        // 32 KB
    float4* tab = (float4*)(bbn + NROWS);             // 8 KB, 16B-aligned
    double* acc = (double*)(tab + TAB_SEGS);          // 8 B

    hipMemsetAsync(acc, 0, sizeof(double), stream);

    lsm_norm_kernel<<<NROWS / 4, 256, 0, stream>>>(src, x_ls, aan);
    lsm_norm_kernel<<<NROWS / 4, 256, 0, stream>>>(tgt, y_ls, bbn);
    build_table_kernel<<<2, 256, 0, stream>>>(tab);
    repack_kernel<<<1024, 256, 0, stream>>>(x_ls, y_ls, xp, yp);

    dim3 grid(NROWS / BM, NROWS / BM, 3);
    pair_kernel<<<grid, 256, 0, stream>>>(xp, yp, aan, bbn, tab, acc);
    finalize_kernel<<<1, 1, 0, stream>>>(acc, out);
}